// Round 2
// baseline (1003.081 us; speedup 1.0000x reference)
//
#include <hip/hip_runtime.h>
#include <stdint.h>

// ---------------------------------------------------------------------------
// QuantLinearNet: y = fq8( fq8(x) @ fq4(W).T + bq )
// Round 5: GEMM ported to 256x256 / 8-wave / phase-split schedule (T3+T4+T5):
//  - double-buffered 128B K-tiles, prefetch issued at iter top,
//    counted s_waitcnt vmcnt(8) -> loads stay in flight across barriers
//  - 4 phases/K-tile: {ds_read subtile; s_barrier; setprio(1); 16 MFMA;
//    setprio(0); s_barrier}
//  - LDS 16B-chunk XOR swizzle byte-identical to proven round-2 kernel
//  - XCD-bijective block swizzle (1024 blocks)
// Elementwise kernels unchanged from round 4.
// ---------------------------------------------------------------------------

typedef __attribute__((ext_vector_type(4))) int i32x4;

#define BM 256
#define BN 256
#define BKB 128  // K-bytes (= i8 elements) per tile

__device__ __forceinline__ void async_copy16(const void* g, void* l) {
  __builtin_amdgcn_global_load_lds((const __attribute__((address_space(1))) void*)g,
                                   (__attribute__((address_space(3))) void*)l,
                                   16, 0, 0);
}

__device__ __forceinline__ float wave_max64(float v) {
#pragma unroll
  for (int off = 32; off > 0; off >>= 1) v = fmaxf(v, __shfl_xor(v, off, 64));
  return v;
}

__device__ __forceinline__ float max4(float4 v) {
  return fmaxf(fmaxf(fabsf(v.x), fabsf(v.y)), fmaxf(fabsf(v.z), fabsf(v.w)));
}

// blocks [0, WBLK) reduce W, the rest reduce x. One launch, two atomics.
#define WBLK 1024
__global__ void maxabs_both(const float4* __restrict__ x, int n4x,
                            const float4* __restrict__ w, int n4w,
                            unsigned* __restrict__ scal) {
  const bool isW = (int)blockIdx.x < WBLK;
  const float4* __restrict__ p = isW ? w : x;
  const int n4 = isW ? n4w : n4x;
  const int bid = isW ? blockIdx.x : blockIdx.x - WBLK;
  const int nb = isW ? WBLK : gridDim.x - WBLK;
  const int stride = nb * blockDim.x;

  float m0 = 0.f, m1 = 0.f, m2 = 0.f, m3 = 0.f;
  int i = bid * blockDim.x + threadIdx.x;
  for (; i + 3 * stride < n4; i += 4 * stride) {
    m0 = fmaxf(m0, max4(p[i]));
    m1 = fmaxf(m1, max4(p[i + stride]));
    m2 = fmaxf(m2, max4(p[i + 2 * stride]));
    m3 = fmaxf(m3, max4(p[i + 3 * stride]));
  }
  for (; i < n4; i += stride) m0 = fmaxf(m0, max4(p[i]));
  float m = wave_max64(fmaxf(fmaxf(m0, m1), fmaxf(m2, m3)));

  __shared__ float wm[4];
  if ((threadIdx.x & 63) == 0) wm[threadIdx.x >> 6] = m;
  __syncthreads();
  if (threadIdx.x == 0)
    atomicMax(&scal[isW ? 1 : 0],
              __float_as_uint(fmaxf(fmaxf(wm[0], wm[1]), fmaxf(wm[2], wm[3]))));
}

__device__ __forceinline__ unsigned pack4(float4 v, float inv, float qmax) {
  unsigned b0 = (unsigned)(int)fminf(fmaxf(rintf(v.x * inv), -qmax), qmax) & 0xffu;
  unsigned b1 = (unsigned)(int)fminf(fmaxf(rintf(v.y * inv), -qmax), qmax) & 0xffu;
  unsigned b2 = (unsigned)(int)fminf(fmaxf(rintf(v.z * inv), -qmax), qmax) & 0xffu;
  unsigned b3 = (unsigned)(int)fminf(fmaxf(rintf(v.w * inv), -qmax), qmax) & 0xffu;
  return b0 | (b1 << 8) | (b2 << 16) | (b3 << 24);
}

// fake-quant fp32 -> int8 codes, fully coalesced (thread i <-> float4 i).
__global__ void quant_both(const float4* __restrict__ x, unsigned* __restrict__ xq, int n4x,
                           const float4* __restrict__ w, unsigned* __restrict__ wq, int n4w,
                           const unsigned* __restrict__ scal) {
  const bool isW = (int)blockIdx.x < WBLK;
  const float4* __restrict__ src = isW ? w : x;
  unsigned* __restrict__ dst = isW ? wq : xq;
  const int n4 = isW ? n4w : n4x;
  const int bid = isW ? blockIdx.x : blockIdx.x - WBLK;
  const int nb = isW ? WBLK : gridDim.x - WBLK;
  const float qmax = isW ? 7.f : 127.f;
  const float inv = qmax / __uint_as_float(scal[isW ? 1 : 0]);
  const int stride = nb * blockDim.x;

  int i = bid * blockDim.x + threadIdx.x;
  for (; i + stride < n4; i += 2 * stride) {
    float4 a = src[i];
    float4 b = src[i + stride];
    dst[i] = pack4(a, inv, qmax);
    dst[i + stride] = pack4(b, inv, qmax);
  }
  if (i < n4) dst[i] = pack4(src[i], inv, qmax);
}

// Stage one 256x128B tile pair (A,B) into LDS. 8 gload_lds per thread.
// LDS dest linear (gload_lds constraint); global src chunk-XOR-swizzled.
__device__ __forceinline__ void stage_tile(const uint8_t* __restrict__ Aq,
                                           const uint8_t* __restrict__ Bq,
                                           uint8_t* sa, uint8_t* sb,
                                           int t, int K, int bm, int bn, int k0) {
#pragma unroll
  for (int j = 0; j < 4; ++j) {
    const int id = j * 512 + t;          // 16B chunk id (2048 per matrix)
    const int r = id >> 3;               // row (8 chunks/row)
    const int cc = id & 7;               // LDS chunk position in row
    const int gc = (cc ^ (r & 7)) << 4;  // swizzled global byte offset
    async_copy16(Aq + (size_t)(bm + r) * K + k0 + gc, sa + id * 16);
  }
#pragma unroll
  for (int j = 0; j < 4; ++j) {
    const int id = j * 512 + t;
    const int r = id >> 3;
    const int cc = id & 7;
    const int gc = (cc ^ (r & 7)) << 4;
    async_copy16(Bq + (size_t)(bn + r) * K + k0 + gc, sb + id * 16);
  }
}

// C[m,n] = sum_k A[m,k]*B[n,k], A/B int8 codes, K-major.
__global__ __launch_bounds__(512, 2) void gemm_i8(
    const uint8_t* __restrict__ Aq, const uint8_t* __restrict__ Bq,
    const float* __restrict__ bias, float* __restrict__ Out,
    unsigned* __restrict__ scal, int M, int N, int K) {
  __shared__ uint8_t sA[2][BM * BKB];
  __shared__ uint8_t sB[2][BN * BKB];
  __shared__ float wred[8];

  const int t = threadIdx.x;
  const int lane = t & 63, wave = t >> 6;
  const int wm = wave >> 2, wn = wave & 3;  // 2 x 4 waves, each owns 128x64
  const int quad = lane >> 4, l16 = lane & 15;

  // XCD-bijective swizzle: 1024 blocks, 1024 % 8 == 0.
  const int nwg = (int)gridDim.x;
  const int wg = ((int)blockIdx.x & 7) * (nwg >> 3) + ((int)blockIdx.x >> 3);
  const int nbx = N / BN;
  const int bm = (wg / nbx) * BM, bn = (wg % nbx) * BN;

  i32x4 acc[8][4] = {};
  const int NT = K >> 7;

  stage_tile(Aq, Bq, sA[0], sB[0], t, K, bm, bn, 0);

  for (int tt = 0; tt < NT; ++tt) {
    const int cur = tt & 1;
    if (tt + 1 < NT) {
      stage_tile(Aq, Bq, sA[cur ^ 1], sB[cur ^ 1], t, K, bm, bn, (tt + 1) << 7);
      asm volatile("s_waitcnt vmcnt(8)" ::: "memory");  // tile tt landed; t+1 in flight
    } else {
      asm volatile("s_waitcnt vmcnt(0)" ::: "memory");  // epilogue drain
    }
    asm volatile("s_barrier" ::: "memory");

    const uint8_t* sa = sA[cur];
    const uint8_t* sb = sB[cur];
#pragma unroll
    for (int kk = 0; kk < 2; ++kk) {  // two K=64 slices per 128B tile
      i32x4 bf[4];
#pragma unroll
      for (int nt = 0; nt < 4; ++nt) {
        const int row = wn * 64 + nt * 16 + l16;
        const int p = (quad + kk * 4) ^ (row & 7);
        bf[nt] = *(const i32x4*)&sb[row * BKB + p * 16];
      }
#pragma unroll
      for (int mh = 0; mh < 2; ++mh) {  // phase = one 64x64 C-quadrant slice
        i32x4 af[4];
#pragma unroll
        for (int mt = 0; mt < 4; ++mt) {
          const int row = wm * 128 + mh * 64 + mt * 16 + l16;
          const int p = (quad + kk * 4) ^ (row & 7);
          af[mt] = *(const i32x4*)&sa[row * BKB + p * 16];
        }
        asm volatile("s_barrier" ::: "memory");
        __builtin_amdgcn_s_setprio(1);
#pragma unroll
        for (int mt = 0; mt < 4; ++mt)
#pragma unroll
          for (int nt = 0; nt < 4; ++nt)
            acc[mh * 4 + mt][nt] = __builtin_amdgcn_mfma_i32_16x16x64_i8(
                af[mt], bf[nt], acc[mh * 4 + mt][nt], 0, 0, 0);
        __builtin_amdgcn_s_setprio(0);
        asm volatile("s_barrier" ::: "memory");
      }
    }
  }

  // epilogue: t = acc + round(b/s_b); store integer-valued fp32 t; max|t|
  const float s_in = __uint_as_float(scal[0]) / 127.0f;
  const float s_w = __uint_as_float(scal[1]) / 7.0f;
  const float s_b = s_in * s_w;
  float bi[4];
#pragma unroll
  for (int nt = 0; nt < 4; ++nt) {
    const int n = bn + wn * 64 + nt * 16 + l16;
    bi[nt] = rintf(bias[n] / s_b);
  }
  float lmax = 0.f;
#pragma unroll
  for (int a = 0; a < 8; ++a) {
#pragma unroll
    for (int r = 0; r < 4; ++r) {
      const int m = bm + wm * 128 + a * 16 + quad * 4 + r;
      float* orow = Out + (size_t)m * N + bn + wn * 64 + l16;
#pragma unroll
      for (int nt = 0; nt < 4; ++nt) {
        float tv = (float)acc[a][nt][r] + bi[nt];
        orow[nt * 16] = tv;
        lmax = fmaxf(lmax, fabsf(tv));
      }
    }
  }
  lmax = wave_max64(lmax);
  if (lane == 0) wred[wave] = lmax;
  __syncthreads();
  if (t == 0) {
    float m = wred[0];
#pragma unroll
    for (int i = 1; i < 8; ++i) m = fmaxf(m, wred[i]);
    atomicMax(&scal[2], __float_as_uint(m));
  }
}

__device__ __forceinline__ float4 quantize4(float4 v, float inv, float s_out) {
  v.x = fminf(fmaxf(rintf(v.x * inv), -127.f), 127.f) * s_out;
  v.y = fminf(fmaxf(rintf(v.y * inv), -127.f), 127.f) * s_out;
  v.z = fminf(fmaxf(rintf(v.z * inv), -127.f), 127.f) * s_out;
  v.w = fminf(fmaxf(rintf(v.w * inv), -127.f), 127.f) * s_out;
  return v;
}

__global__ void finalize4(float4* __restrict__ out, int n4, const unsigned* __restrict__ scal) {
  const float s_in = __uint_as_float(scal[0]) / 127.0f;
  const float s_w = __uint_as_float(scal[1]) / 7.0f;
  const float s_b = s_in * s_w;
  const float maxt = __uint_as_float(scal[2]);
  const float s_out = (s_b * maxt) / 127.0f;
  const float inv = 127.0f / maxt;
  const int stride = gridDim.x * blockDim.x;
  int i = blockIdx.x * blockDim.x + threadIdx.x;
  for (; i + stride < n4; i += 2 * stride) {
    float4 a = out[i];
    float4 b = out[i + stride];
    out[i] = quantize4(a, inv, s_out);
    out[i + stride] = quantize4(b, inv, s_out);
  }
  if (i < n4) out[i] = quantize4(out[i], inv, s_out);
}

extern "C" void kernel_launch(void* const* d_in, const int* in_sizes, int n_in,
                              void* d_out, int out_size, void* d_ws, size_t ws_size,
                              hipStream_t stream) {
  const float* x = (const float*)d_in[0];
  const float* W = (const float*)d_in[1];
  const float* b = (const float*)d_in[2];
  float* out = (float*)d_out;

  const int N = in_sizes[2];       // 4096 (H)
  const int K = in_sizes[1] / N;   // 4096 (D)
  const int M = in_sizes[0] / K;   // 16384 (tokens)

  unsigned* scal = (unsigned*)d_ws;
  const size_t OFF = 4096;
  uint8_t* xq = (uint8_t*)d_ws + OFF;  // M*K bytes
  uint8_t* wq = xq + (size_t)M * K;    // N*K bytes

  const int n4x = (M / 4) * K;         // x in float4 units
  const int n4w = (N / 4) * K;         // W in float4 units

  hipMemsetAsync(scal, 0, 16, stream);
  maxabs_both<<<WBLK + 4096, 256, 0, stream>>>((const float4*)x, n4x,
                                               (const float4*)W, n4w, scal);
  quant_both<<<WBLK + 4096, 256, 0, stream>>>((const float4*)x, (unsigned*)xq, n4x,
                                              (const float4*)W, (unsigned*)wq, n4w, scal);

  const int nblk = (M / BM) * (N / BN);  // 64*16 = 1024, % 8 == 0
  gemm_i8<<<nblk, 512, 0, stream>>>(xq, wq, b, out, scal, M, N, K);

  finalize4<<<8192, 256, 0, stream>>>((float4*)out, (int)((size_t)M * N / 4), scal);
}

// Round 4
// 943.257 us; speedup vs baseline: 1.0634x; 1.0634x over previous
//
#include <hip/hip_runtime.h>
#include <stdint.h>

// ---------------------------------------------------------------------------
// QuantLinearNet: y = fq8( fq8(x) @ fq4(W).T + bq )
// Round 7: RESUBMIT of round 6 (container failed twice; audit found no
// hang/race mechanism — disambiguating infra vs kernel).
// GEMM = 256x256, BK=64, 3-buffer LDS ring, true counted-vmcnt pipeline
// (T3+T4+T5):
//  - while computing tile t, stage tile t+2 (A in phase0, B in phase1)
//  - tile fence = s_waitcnt vmcnt(4) BEFORE trailing barrier: next tile's
//    loads landed, newest tile's 4 loads stay in flight across barriers
//  - 2 phases/tile: {ds_read frags; stage; barrier; setprio1; 16 MFMA;
//    setprio0; [vmcnt]; barrier}
//  - LDS packs 2 rows/128B line, XOR over 8 chunk slots; stage permutation
//    and frag_ptr are exact inverses; every consecutive-8-lane service
//    group covers all 8 slots once (conflict-free, same property as the
//    proven round-2 layout)
// Elementwise kernels unchanged.
// ---------------------------------------------------------------------------

typedef __attribute__((ext_vector_type(4))) int i32x4;

#define BM 256
#define BN 256
#define BKB 64  // K-bytes per tile

__device__ __forceinline__ void async_copy16(const void* g, void* l) {
  __builtin_amdgcn_global_load_lds((const __attribute__((address_space(1))) void*)g,
                                   (__attribute__((address_space(3))) void*)l,
                                   16, 0, 0);
}

__device__ __forceinline__ float wave_max64(float v) {
#pragma unroll
  for (int off = 32; off > 0; off >>= 1) v = fmaxf(v, __shfl_xor(v, off, 64));
  return v;
}

__device__ __forceinline__ float max4(float4 v) {
  return fmaxf(fmaxf(fabsf(v.x), fabsf(v.y)), fmaxf(fabsf(v.z), fabsf(v.w)));
}

// blocks [0, WBLK) reduce W, the rest reduce x. One launch, two atomics.
#define WBLK 1024
__global__ void maxabs_both(const float4* __restrict__ x, int n4x,
                            const float4* __restrict__ w, int n4w,
                            unsigned* __restrict__ scal) {
  const bool isW = (int)blockIdx.x < WBLK;
  const float4* __restrict__ p = isW ? w : x;
  const int n4 = isW ? n4w : n4x;
  const int bid = isW ? blockIdx.x : blockIdx.x - WBLK;
  const int nb = isW ? WBLK : gridDim.x - WBLK;
  const int stride = nb * blockDim.x;

  float m0 = 0.f, m1 = 0.f, m2 = 0.f, m3 = 0.f;
  int i = bid * blockDim.x + threadIdx.x;
  for (; i + 3 * stride < n4; i += 4 * stride) {
    m0 = fmaxf(m0, max4(p[i]));
    m1 = fmaxf(m1, max4(p[i + stride]));
    m2 = fmaxf(m2, max4(p[i + 2 * stride]));
    m3 = fmaxf(m3, max4(p[i + 3 * stride]));
  }
  for (; i < n4; i += stride) m0 = fmaxf(m0, max4(p[i]));
  float m = wave_max64(fmaxf(fmaxf(m0, m1), fmaxf(m2, m3)));

  __shared__ float wm[4];
  if ((threadIdx.x & 63) == 0) wm[threadIdx.x >> 6] = m;
  __syncthreads();
  if (threadIdx.x == 0)
    atomicMax(&scal[isW ? 1 : 0],
              __float_as_uint(fmaxf(fmaxf(wm[0], wm[1]), fmaxf(wm[2], wm[3]))));
}

__device__ __forceinline__ unsigned pack4(float4 v, float inv, float qmax) {
  unsigned b0 = (unsigned)(int)fminf(fmaxf(rintf(v.x * inv), -qmax), qmax) & 0xffu;
  unsigned b1 = (unsigned)(int)fminf(fmaxf(rintf(v.y * inv), -qmax), qmax) & 0xffu;
  unsigned b2 = (unsigned)(int)fminf(fmaxf(rintf(v.z * inv), -qmax), qmax) & 0xffu;
  unsigned b3 = (unsigned)(int)fminf(fmaxf(rintf(v.w * inv), -qmax), qmax) & 0xffu;
  return b0 | (b1 << 8) | (b2 << 16) | (b3 << 24);
}

// fake-quant fp32 -> int8 codes, fully coalesced (thread i <-> float4 i).
__global__ void quant_both(const float4* __restrict__ x, unsigned* __restrict__ xq, int n4x,
                           const float4* __restrict__ w, unsigned* __restrict__ wq, int n4w,
                           const unsigned* __restrict__ scal) {
  const bool isW = (int)blockIdx.x < WBLK;
  const float4* __restrict__ src = isW ? w : x;
  unsigned* __restrict__ dst = isW ? wq : xq;
  const int n4 = isW ? n4w : n4x;
  const int bid = isW ? blockIdx.x : blockIdx.x - WBLK;
  const int nb = isW ? WBLK : gridDim.x - WBLK;
  const float qmax = isW ? 7.f : 127.f;
  const float inv = qmax / __uint_as_float(scal[isW ? 1 : 0]);
  const int stride = nb * blockDim.x;

  int i = bid * blockDim.x + threadIdx.x;
  for (; i + stride < n4; i += 2 * stride) {
    float4 a = src[i];
    float4 b = src[i + stride];
    dst[i] = pack4(a, inv, qmax);
    dst[i + stride] = pack4(b, inv, qmax);
  }
  if (i < n4) dst[i] = pack4(src[i], inv, qmax);
}

// Stage one 256x64B matrix tile into an LDS ring slot. 2 gload_lds/thread.
// LDS layout: 128B line = 2 rows; logical chunk cl = (r&1)*4 + c stored at
// slot pl = cl ^ (L&7). Dest linear in id (gload_lds constraint); the
// permutation is applied to the global source address.
__device__ __forceinline__ void stage_mat(const uint8_t* __restrict__ src,
                                          uint8_t* dst, int t, int K,
                                          int brow, int k0) {
#pragma unroll
  for (int j = 0; j < 2; ++j) {
    const int id = j * 512 + t;       // 1024 chunks of 16B
    const int L = id >> 3;            // line (2 rows)
    const int pl = id & 7;            // LDS slot within line
    const int cl = pl ^ (L & 7);      // logical chunk within line
    const int r = L * 2 + (cl >> 2);  // row
    const int c = cl & 3;             // 16B chunk within row
    async_copy16(src + (size_t)(brow + r) * K + k0 + c * 16, dst + id * 16);
  }
}

// fragment address for row, k-chunk 'quad' under the line-packed XOR layout
__device__ __forceinline__ const i32x4* frag_ptr(const uint8_t* base, int row, int quad) {
  const int L = row >> 1;
  const int p = (((row & 1) << 2) | quad) ^ (L & 7);
  return (const i32x4*)(base + L * 128 + p * 16);
}

// C[m,n] = sum_k A[m,k]*B[n,k], A/B int8 codes, K-major.
__global__ __launch_bounds__(512, 2) void gemm_i8(
    const uint8_t* __restrict__ Aq, const uint8_t* __restrict__ Bq,
    const float* __restrict__ bias, float* __restrict__ Out,
    unsigned* __restrict__ scal, int M, int N, int K) {
  __shared__ uint8_t sA[3][BM * BKB];  // 48 KiB
  __shared__ uint8_t sB[3][BN * BKB];  // 48 KiB
  __shared__ float wred[8];

  const int t = threadIdx.x;
  const int lane = t & 63, wave = t >> 6;
  const int wm = wave >> 2, wn = wave & 3;  // 2 x 4 waves, each owns 128x64
  const int quad = lane >> 4, l16 = lane & 15;

  // XCD-bijective swizzle: 1024 blocks, 1024 % 8 == 0.
  const int nwg = (int)gridDim.x;
  const int wg = ((int)blockIdx.x & 7) * (nwg >> 3) + ((int)blockIdx.x >> 3);
  const int nbx = N / BN;
  const int bm = (wg / nbx) * BM, bn = (wg % nbx) * BN;

  i32x4 acc[8][4] = {};
  const int NT = K >> 6;  // 64 tiles

  // prologue: tiles 0 and 1 staged; fence tile 0, keep tile 1 in flight
  stage_mat(Aq, sA[0], t, K, bm, 0);
  stage_mat(Bq, sB[0], t, K, bn, 0);
  stage_mat(Aq, sA[1], t, K, bm, BKB);
  stage_mat(Bq, sB[1], t, K, bn, BKB);
  asm volatile("s_waitcnt vmcnt(4)" ::: "memory");
  asm volatile("s_barrier" ::: "memory");

  for (int tt = 0; tt < NT; ++tt) {
    const int cur = tt % 3;
    const int nxt = (tt + 2) % 3;
    const uint8_t* sa = sA[cur];
    const uint8_t* sb = sB[cur];
    const bool pf = (tt + 2) < NT;

    // ---- phase 0: B-frags + A-half0; stage A of tile tt+2 ----
    i32x4 bf[4], af[4];
#pragma unroll
    for (int nt = 0; nt < 4; ++nt)
      bf[nt] = *frag_ptr(sb, wn * 64 + nt * 16 + l16, quad);
#pragma unroll
    for (int mt = 0; mt < 4; ++mt)
      af[mt] = *frag_ptr(sa, wm * 128 + mt * 16 + l16, quad);
    if (pf) stage_mat(Aq, sA[nxt], t, K, bm, (tt + 2) << 6);
    asm volatile("s_barrier" ::: "memory");
    __builtin_amdgcn_s_setprio(1);
#pragma unroll
    for (int mt = 0; mt < 4; ++mt)
#pragma unroll
      for (int nt = 0; nt < 4; ++nt)
        acc[mt][nt] = __builtin_amdgcn_mfma_i32_16x16x64_i8(af[mt], bf[nt], acc[mt][nt], 0, 0, 0);
    __builtin_amdgcn_s_setprio(0);
    asm volatile("s_barrier" ::: "memory");

    // ---- phase 1: A-half1; stage B of tile tt+2 ----
    i32x4 ag[4];
#pragma unroll
    for (int mt = 0; mt < 4; ++mt)
      ag[mt] = *frag_ptr(sa, wm * 128 + 64 + mt * 16 + l16, quad);
    if (pf) stage_mat(Bq, sB[nxt], t, K, bn, (tt + 2) << 6);
    asm volatile("s_barrier" ::: "memory");
    __builtin_amdgcn_s_setprio(1);
#pragma unroll
    for (int mt = 0; mt < 4; ++mt)
#pragma unroll
      for (int nt = 0; nt < 4; ++nt)
        acc[4 + mt][nt] = __builtin_amdgcn_mfma_i32_16x16x64_i8(ag[mt], bf[nt], acc[4 + mt][nt], 0, 0, 0);
    __builtin_amdgcn_s_setprio(0);
    // fence: tile tt+1's 4 loads landed; tile tt+2's 4 stay in flight
    if (pf) {
      asm volatile("s_waitcnt vmcnt(4)" ::: "memory");
    } else if (tt + 1 < NT) {
      asm volatile("s_waitcnt vmcnt(0)" ::: "memory");
    }
    asm volatile("s_barrier" ::: "memory");
  }

  // epilogue: t = acc + round(b/s_b); store integer-valued fp32 t; max|t|
  const float s_in = __uint_as_float(scal[0]) / 127.0f;
  const float s_w = __uint_as_float(scal[1]) / 7.0f;
  const float s_b = s_in * s_w;
  float bi[4];
#pragma unroll
  for (int nt = 0; nt < 4; ++nt) {
    const int n = bn + wn * 64 + nt * 16 + l16;
    bi[nt] = rintf(bias[n] / s_b);
  }
  float lmax = 0.f;
#pragma unroll
  for (int a = 0; a < 8; ++a) {
#pragma unroll
    for (int r = 0; r < 4; ++r) {
      const int m = bm + wm * 128 + a * 16 + quad * 4 + r;
      float* orow = Out + (size_t)m * N + bn + wn * 64 + l16;
#pragma unroll
      for (int nt = 0; nt < 4; ++nt) {
        float tv = (float)acc[a][nt][r] + bi[nt];
        orow[nt * 16] = tv;
        lmax = fmaxf(lmax, fabsf(tv));
      }
    }
  }
  lmax = wave_max64(lmax);
  if (lane == 0) wred[wave] = lmax;
  __syncthreads();
  if (t == 0) {
    float m = wred[0];
#pragma unroll
    for (int i = 1; i < 8; ++i) m = fmaxf(m, wred[i]);
    atomicMax(&scal[2], __float_as_uint(m));
  }
}

__device__ __forceinline__ float4 quantize4(float4 v, float inv, float s_out) {
  v.x = fminf(fmaxf(rintf(v.x * inv), -127.f), 127.f) * s_out;
  v.y = fminf(fmaxf(rintf(v.y * inv), -127.f), 127.f) * s_out;
  v.z = fminf(fmaxf(rintf(v.z * inv), -127.f), 127.f) * s_out;
  v.w = fminf(fmaxf(rintf(v.w * inv), -127.f), 127.f) * s_out;
  return v;
}

__global__ void finalize4(float4* __restrict__ out, int n4, const unsigned* __restrict__ scal) {
  const float s_in = __uint_as_float(scal[0]) / 127.0f;
  const float s_w = __uint_as_float(scal[1]) / 7.0f;
  const float s_b = s_in * s_w;
  const float maxt = __uint_as_float(scal[2]);
  const float s_out = (s_b * maxt) / 127.0f;
  const float inv = 127.0f / maxt;
  const int stride = gridDim.x * blockDim.x;
  int i = blockIdx.x * blockDim.x + threadIdx.x;
  for (; i + stride < n4; i += 2 * stride) {
    float4 a = out[i];
    float4 b = out[i + stride];
    out[i] = quantize4(a, inv, s_out);
    out[i + stride] = quantize4(b, inv, s_out);
  }
  if (i < n4) out[i] = quantize4(out[i], inv, s_out);
}

extern "C" void kernel_launch(void* const* d_in, const int* in_sizes, int n_in,
                              void* d_out, int out_size, void* d_ws, size_t ws_size,
                              hipStream_t stream) {
  const float* x = (const float*)d_in[0];
  const float* W = (const float*)d_in[1];
  const float* b = (const float*)d_in[2];
  float* out = (float*)d_out;

  const int N = in_sizes[2];       // 4096 (H)
  const int K = in_sizes[1] / N;   // 4096 (D)
  const int M = in_sizes[0] / K;   // 16384 (tokens)

  unsigned* scal = (unsigned*)d_ws;
  const size_t OFF = 4096;
  uint8_t* xq = (uint8_t*)d_ws + OFF;  // M*K bytes
  uint8_t* wq = xq + (size_t)M * K;    // N*K bytes

  const int n4x = (M / 4) * K;         // x in float4 units
  const int n4w = (N / 4) * K;         // W in float4 units

  hipMemsetAsync(scal, 0, 16, stream);
  maxabs_both<<<WBLK + 4096, 256, 0, stream>>>((const float4*)x, n4x,
                                               (const float4*)W, n4w, scal);
  quant_both<<<WBLK + 4096, 256, 0, stream>>>((const float4*)x, (unsigned*)xq, n4x,
                                              (const float4*)W, (unsigned*)wq, n4w, scal);

  const int nblk = (M / BM) * (N / BN);  // 64*16 = 1024, % 8 == 0
  gemm_i8<<<nblk, 512, 0, stream>>>(xq, wq, b, out, scal, M, N, K);

  finalize4<<<8192, 256, 0, stream>>>((float4*)out, (int)((size_t)M * N / 4), scal);
}